// Round 2
// baseline (1046.924 us; speedup 1.0000x reference)
//
#include <hip/hip_runtime.h>
#include <hip/hip_bf16.h>
#include <stdint.h>

typedef __bf16 bf16;
typedef __bf16 bf16x8 __attribute__((ext_vector_type(8)));
typedef float f32x4 __attribute__((ext_vector_type(4)));
typedef unsigned short u16t;
typedef unsigned int u32t;

#define MFMA16(a, b, c) __builtin_amdgcn_mfma_f32_16x16x32_bf16((a), (b), (c), 0, 0, 0)

typedef const void __attribute__((address_space(1))) cg_void;
typedef void __attribute__((address_space(3))) lds_void;
#define GLL16(g, l) __builtin_amdgcn_global_load_lds((cg_void*)(g), (lds_void*)(l), 16, 0, 0)
#define VWAIT(n) asm volatile("s_waitcnt vmcnt(" #n ")" ::: "memory")

// ---------------- ws layout (bytes) ----------------
#define OFF_FLAG   0
#define OFF_BQKV   256
#define OFF_BPROJ  6400
#define OFF_WQKVT  8448
#define OFF_WPROJT 1581312
#define OFF_QKV    2105600
#define OFF_ATTN   404758784
// xb (bf16 copy of x) aliases OFF_ATTN: lifetime-disjoint.
#define OFF_XB     404758784

// ---------------- dtype detector ----------------
__global__ __launch_bounds__(256) void k_detect(const u16t* x, u32t* flag) {
    __shared__ int cnt;
    if (threadIdx.x == 0) cnt = 0;
    __syncthreads();
    u16t h = x[threadIdx.x * 2];
    int e = (h >> 7) & 0xFF;
    int ok = (h == 0) || (e >= 100 && e <= 134);
    atomicAdd(&cnt, ok);
    __syncthreads();
    if (threadIdx.x == 0) flag[0] = (cnt >= 200) ? 1u : 0u;
}

// ---------------- x f32 -> bf16 pre-pass (skipped when input already bf16) ----
__global__ __launch_bounds__(256) void k_cvt(const float* x, bf16* xb, const u32t* flagp) {
    if (flagp[0]) return;
    const size_t TOT = (size_t)131072 * 512;
    size_t i = (size_t)(blockIdx.x * 256 + threadIdx.x) * 8;
    const size_t stride = (size_t)gridDim.x * 256 * 8;
    for (; i < TOT; i += stride) {
        float4 v0 = *(const float4*)(x + i);
        float4 v1 = *(const float4*)(x + i + 4);
        bf16x8 h;
        h[0] = (bf16)v0.x; h[1] = (bf16)v0.y; h[2] = (bf16)v0.z; h[3] = (bf16)v0.w;
        h[4] = (bf16)v1.x; h[5] = (bf16)v1.y; h[6] = (bf16)v1.z; h[7] = (bf16)v1.w;
        *(bf16x8*)(xb + i) = h;
    }
}

// ---------------- weight transpose: W[512][N] -> Wt[N][512] bf16 ----------------
template <int N>
__global__ __launch_bounds__(256) void k_trans(const void* W, bf16* Wt, const u32t* flagp) {
    __shared__ float T[64][65];
    const int isbf = (int)flagp[0];
    const int n0 = blockIdx.x * 64, k0 = blockIdx.y * 64;
    const int t = threadIdx.x;
    const int lc = t & 63, lr = t >> 6;
#pragma unroll
    for (int rr = 0; rr < 16; ++rr) {
        int row = rr * 4 + lr;
        size_t g = (size_t)(k0 + row) * N + n0 + lc;
        float v = isbf ? (float)((const bf16*)W)[g] : ((const float*)W)[g];
        T[row][lc] = v;
    }
    __syncthreads();
#pragma unroll
    for (int rr = 0; rr < 16; ++rr) {
        int row = rr * 4 + lr;
        Wt[(size_t)(n0 + row) * 512 + k0 + lc] = (bf16)T[lc][row];
    }
}

// ---------------- bias prep -> f32 ----------------
__global__ __launch_bounds__(256) void k_bias(const void* b_qkv, const void* b_proj,
                                              const u32t* flagp, char* ws) {
    float* bq = (float*)(ws + OFF_BQKV);
    float* bp = (float*)(ws + OFF_BPROJ);
    const int isbf = (int)flagp[0];
    int gid = blockIdx.x * 256 + threadIdx.x;
    if (gid < 1536)
        bq[gid] = isbf ? (float)((const bf16*)b_qkv)[gid] : ((const float*)b_qkv)[gid];
    else if (gid < 2048) {
        int o = gid - 1536;
        bp[o] = isbf ? (float)((const bf16*)b_proj)[o] : ((const float*)b_proj)[o];
    }
}

// ---------------- GEMM: C[M][NTOT] = A[M][512] * Bt[NTOT][512]^T + bias ----------------
// 128x128 tile, BK=32, 256 threads (4 waves each 64x64), XCD-swizzled flat grid.
// T3+T4: 4 LDS buffers (depth-3 prefetch), ONE raw s_barrier per K-step, counted
// vmcnt(8) (= 2 stages x 4 loads left in flight) -- never drain to 0 in main loop.
// Iter t: vmcnt(wait stage t done); barrier; STAGE(t+3); COMPUTE(t).
//   - STAGE(t+3) overwrites buf[(t+3)&3], last read by COMPUTE(t-1) BEFORE
//     barrier-t  -> safe.  COMPUTE(t)'s buffer protected from STAGE(t+4) by
//     barrier-(t+1).  Accumulation order identical to previous rounds.
// LDS chunk swizzle: logical chunk c of row r stored at phys pc = c ^ f(r),
// f(r) = (r ^ (r>>2)) & 3  -> fragment ds_read_b128 conflict-free.
template <int NTOT>
__global__ __launch_bounds__(256) void k_gemm(const void* Ax, const bf16* Axb, const bf16* Bt,
                                              const float* bias, void* Cp,
                                              const u32t* flagp, int omode) {
    __shared__ __align__(16) u16t As[4][4096];
    __shared__ __align__(16) u16t Bs[4][4096];
    constexpr int NBN = NTOT / 128;
    const int isbf = (int)flagp[0];
    const int out_bf16 = (omode == 1) || isbf;
    const bf16* Ab = isbf ? (const bf16*)Ax : Axb;

    const int t = threadIdx.x;
    const int w = t >> 6, lane = t & 63;
    const int ln = lane & 15, qd = lane >> 4;

    // XCD-aware swizzle: all NBN blocks of an m-group land on one XCD
    const int flat = blockIdx.x;
    const int xcd = flat & 7, slot = flat >> 3;
    const int n_idx = slot % NBN, grp = slot / NBN;
    const int m0 = (grp * 8 + xcd) * 128;
    const int n0 = n_idx * 128;
    const int wr = (w >> 1) * 64, wc = (w & 1) * 64;

    // staging: tile = 128 rows x 4 chunks of 16B = 512 chunks; 2 per thread per matrix
    u32t aoff[2], boff[2];
    int lbase[2];
#pragma unroll
    for (int q = 0; q < 2; ++q) {
        int phys = q * 256 + w * 64 + lane;
        int r = phys >> 2, pc = phys & 3;
        int c = pc ^ ((r ^ (r >> 2)) & 3);
        lbase[q] = (q * 256 + w * 64) * 8;            // u16 index of wave-uniform dest
        aoff[q] = (u32t)(m0 + r) * 512 + c * 8;
        boff[q] = (u32t)(n0 + r) * 512 + c * 8;
    }
    // fragment LDS offsets (u16 units): row ra, chunk qd -> phys qd ^ f(ra)
    int afo[4], bfo[4];
#pragma unroll
    for (int i = 0; i < 4; ++i) {
        int ra = wr + i * 16 + ln;
        afo[i] = ra * 32 + (qd ^ ((ra ^ (ra >> 2)) & 3)) * 8;
        int rb = wc + i * 16 + ln;
        bfo[i] = rb * 32 + (qd ^ ((rb ^ (rb >> 2)) & 3)) * 8;
    }

    f32x4 acc[4][4];
    f32x4 zero = {0.f, 0.f, 0.f, 0.f};
#pragma unroll
    for (int i = 0; i < 4; ++i)
#pragma unroll
        for (int j = 0; j < 4; ++j) acc[i][j] = zero;

    auto STAGE = [&](int buf, int kt) {
#pragma unroll
        for (int q = 0; q < 2; ++q)
            GLL16(Ab + aoff[q] + kt * 32, &As[buf][lbase[q]]);
#pragma unroll
        for (int q = 0; q < 2; ++q)
            GLL16(Bt + boff[q] + kt * 32, &Bs[buf][lbase[q]]);
    };
    auto COMPUTE = [&](int buf) {
        bf16x8 af[4], bfr[4];
#pragma unroll
        for (int i = 0; i < 4; ++i) af[i] = *(const bf16x8*)(void*)&As[buf][afo[i]];
#pragma unroll
        for (int j = 0; j < 4; ++j) bfr[j] = *(const bf16x8*)(void*)&Bs[buf][bfo[j]];
        __builtin_amdgcn_s_setprio(1);
#pragma unroll
        for (int i = 0; i < 4; ++i)
#pragma unroll
            for (int j = 0; j < 4; ++j) acc[i][j] = MFMA16(af[i], bfr[j], acc[i][j]);
        __builtin_amdgcn_s_setprio(0);
    };

    STAGE(0, 0);
    STAGE(1, 1);
    STAGE(2, 2);   // 12 loads outstanding
#pragma unroll
    for (int kt = 0; kt < 16; ++kt) {
        if (kt < 14) VWAIT(8);        // stage-kt done; 2 stages stay in flight
        else if (kt == 14) VWAIT(4);
        else VWAIT(0);
        __builtin_amdgcn_s_barrier();
        if (kt + 3 < 16) STAGE((kt + 3) & 3, kt + 3);
        COMPUTE(kt & 3);
    }

    float bj[4];
#pragma unroll
    for (int j = 0; j < 4; ++j) bj[j] = bias[n0 + wc + j * 16 + ln];

    if (out_bf16) {
        bf16* C = (bf16*)Cp;
#pragma unroll
        for (int i = 0; i < 4; ++i)
#pragma unroll
            for (int j = 0; j < 4; ++j)
#pragma unroll
                for (int rr = 0; rr < 4; ++rr) {
                    size_t row = (size_t)m0 + wr + i * 16 + qd * 4 + rr;
                    int col = n0 + wc + j * 16 + ln;
                    C[row * NTOT + col] = (bf16)(acc[i][j][rr] + bj[j]);
                }
    } else {
        float* C = (float*)Cp;
#pragma unroll
        for (int i = 0; i < 4; ++i)
#pragma unroll
            for (int j = 0; j < 4; ++j)
#pragma unroll
                for (int rr = 0; rr < 4; ++rr) {
                    size_t row = (size_t)m0 + wr + i * 16 + qd * 4 + rr;
                    int col = n0 + wc + j * 16 + ln;
                    C[row * NTOT + col] = acc[i][j][rr] + bj[j];
                }
    }
}

// ---------------- fused gaussian-window attention: one wave per (b,h) ----------------
// V now staged to LDS via 4 wave-local GLL16 (issued before QK^T, drained by a
// per-wave vmcnt(0) -- no barrier needed), replacing 32 scalar global bf16 loads.
// V LDS swizzle: chunk c of row r at phys c ^ fv(r), fv(r) = ((r>>3) ^ r) & 3,
// so the 4 qd-quads (rows q8+jj differing by 8) hit distinct chunk slots.
__global__ __launch_bounds__(256) void k_attn(const bf16* qkv, bf16* attn) {
    __shared__ __align__(16) bf16 P[4][64 * 72];
    __shared__ __align__(16) u16t Vs[4][2048];   // 4 KB per wave: V[64][32] swizzled
    const int t = threadIdx.x;
    const int w = t >> 6, lane = t & 63;
    const int ln = lane & 15, qd = lane >> 4, q8 = qd * 8;
    const int flat = blockIdx.x;
    const int xcd = flat & 7, slot = flat >> 3;
    const int sub = slot & 3, grp = slot >> 2;
    const int b = grp * 8 + xcd;
    const int h = sub * 4 + w;
    const size_t rowbase = (size_t)b * 64 * 1536;
    const int colq = h * 32 + q8;

    bf16x8 aq[4], bk[4];
#pragma unroll
    for (int i = 0; i < 4; ++i)
        aq[i] = *(const bf16x8*)(qkv + rowbase + (size_t)(i * 16 + ln) * 1536 + colq);
#pragma unroll
    for (int j = 0; j < 4; ++j)
        bk[j] = *(const bf16x8*)(qkv + rowbase + (size_t)(j * 16 + ln) * 1536 + 512 + colq);

    // V stage: phys chunk = q*64+lane; r = phys>>2, pc = phys&3, logical c = pc ^ fv(r)
#pragma unroll
    for (int q = 0; q < 4; ++q) {
        int r = q * 16 + (lane >> 2), pc = lane & 3;
        int c = pc ^ (((r >> 3) ^ r) & 3);
        GLL16(qkv + rowbase + (size_t)r * 1536 + 1024 + h * 32 + c * 8, &Vs[w][q * 512]);
    }

    f32x4 zero = {0.f, 0.f, 0.f, 0.f};
    f32x4 s[4][4];
#pragma unroll
    for (int i = 0; i < 4; ++i)
#pragma unroll
        for (int j = 0; j < 4; ++j) s[i][j] = MFMA16(aq[i], bk[j], zero);

    const float INV2S2 = 3.28731097961867f;   // 1/(2*0.39^2)
    {
        int c = lane & 7;
        float S1 = 0.f;
#pragma unroll
        for (int c2 = 0; c2 < 8; ++c2) {
            int d = c - c2;
            S1 += __expf(-(float)(d * d) * INV2S2);
        }
        float invS1 = 1.0f / S1;
        const int ymb = ln >> 3, xm = ln & 7, yq = qd >> 1, xq = (qd & 1) * 4;
        float FY[4][4], FX[4];
#pragma unroll
        for (int i = 0; i < 4; ++i) {
            int yn = 2 * i + yq;
            float g = __shfl(invS1, yn, 64);
#pragma unroll
            for (int j = 0; j < 4; ++j) {
                int dy = yn - (2 * j + ymb);
                FY[i][j] = __expf(-(float)(dy * dy) * INV2S2) * g;
            }
        }
#pragma unroll
        for (int rr = 0; rr < 4; ++rr) {
            int xn = xq + rr;
            int dx = xn - xm;
            FX[rr] = __expf(-(float)(dx * dx) * INV2S2) * __shfl(invS1, xn, 64);
        }

        const float SCALE = 0.17677669529663687f;  // 1/sqrt(32)
#pragma unroll
        for (int i = 0; i < 4; ++i)
#pragma unroll
            for (int rr = 0; rr < 4; ++rr) {
                float lj[4];
                float mx = -1e30f;
#pragma unroll
                for (int j = 0; j < 4; ++j) {
                    lj[j] = s[i][j][rr] * SCALE * FY[i][j] * FX[rr];
                    mx = fmaxf(mx, lj[j]);
                }
                mx = fmaxf(mx, __shfl_xor(mx, 1));
                mx = fmaxf(mx, __shfl_xor(mx, 2));
                mx = fmaxf(mx, __shfl_xor(mx, 4));
                mx = fmaxf(mx, __shfl_xor(mx, 8));
                float sum = 0.f;
#pragma unroll
                for (int j = 0; j < 4; ++j) {
                    lj[j] = __expf(lj[j] - mx);
                    sum += lj[j];
                }
                sum += __shfl_xor(sum, 1);
                sum += __shfl_xor(sum, 2);
                sum += __shfl_xor(sum, 4);
                sum += __shfl_xor(sum, 8);
                float inv = 1.0f / sum;
                int n = i * 16 + qd * 4 + rr;
#pragma unroll
                for (int j = 0; j < 4; ++j)
                    P[w][n * 72 + j * 16 + ln] = (bf16)(lj[j] * inv);
            }
    }

    VWAIT(0);   // wave-local V tile staged; no barrier needed (no cross-wave sharing)

    f32x4 o[4][2];
#pragma unroll
    for (int i = 0; i < 4; ++i) {
        o[i][0] = zero;
        o[i][1] = zero;
    }
#pragma unroll
    for (int kc = 0; kc < 64; kc += 32) {
        bf16x8 bv[2];
#pragma unroll
        for (int j2 = 0; j2 < 2; ++j2) {
            int cc = j2 * 2 + (ln >> 3);
#pragma unroll
            for (int jj = 0; jj < 8; ++jj) {
                int rv = kc + q8 + jj;
                bv[j2][jj] = *(const bf16*)&Vs[w][rv * 32 + (cc ^ (((rv >> 3) ^ rv) & 3)) * 8 + (ln & 7)];
            }
        }
#pragma unroll
        for (int i = 0; i < 4; ++i) {
            bf16x8 ap = *(const bf16x8*)(void*)&P[w][(i * 16 + ln) * 72 + kc + q8];
#pragma unroll
            for (int j2 = 0; j2 < 2; ++j2) o[i][j2] = MFMA16(ap, bv[j2], o[i][j2]);
        }
    }
#pragma unroll
    for (int i = 0; i < 4; ++i)
#pragma unroll
        for (int j2 = 0; j2 < 2; ++j2)
#pragma unroll
            for (int rr = 0; rr < 4; ++rr)
                attn[((size_t)b * 64 + i * 16 + qd * 4 + rr) * 512 + h * 32 + j2 * 16 + ln] =
                    (bf16)(o[i][j2][rr]);
}

extern "C" void kernel_launch(void* const* d_in, const int* in_sizes, int n_in,
                              void* d_out, int out_size, void* d_ws, size_t ws_size,
                              hipStream_t stream) {
    const void* x = d_in[0];
    const void* w_qkv = d_in[1];
    const void* b_qkv = d_in[2];
    const void* w_proj = d_in[3];
    const void* b_proj = d_in[4];
    char* ws = (char*)d_ws;
    u32t* flag = (u32t*)(ws + OFF_FLAG);
    bf16* wqkvT = (bf16*)(ws + OFF_WQKVT);
    bf16* wprojT = (bf16*)(ws + OFF_WPROJT);
    float* bq = (float*)(ws + OFF_BQKV);
    float* bp = (float*)(ws + OFF_BPROJ);
    bf16* qkv = (bf16*)(ws + OFF_QKV);
    bf16* attn = (bf16*)(ws + OFF_ATTN);
    bf16* xb = (bf16*)(ws + OFF_XB);   // aliases attn region (disjoint lifetime)

    k_detect<<<1, 256, 0, stream>>>((const u16t*)x, flag);
    k_cvt<<<2048, 256, 0, stream>>>((const float*)x, xb, flag);
    k_trans<1536><<<dim3(24, 8), 256, 0, stream>>>(w_qkv, wqkvT, flag);
    k_trans<512><<<dim3(8, 8), 256, 0, stream>>>(w_proj, wprojT, flag);
    k_bias<<<8, 256, 0, stream>>>(b_qkv, b_proj, flag, ws);
    // QKV GEMM: [131072,512] @ [512,1536] -> qkv bf16
    k_gemm<1536><<<12288, 256, 0, stream>>>(x, xb, wqkvT, bq, qkv, flag, 1);
    // attention
    k_attn<<<8192, 256, 0, stream>>>(qkv, attn);
    // proj GEMM: [131072,512] @ [512,512] -> d_out
    k_gemm<512><<<4096, 256, 0, stream>>>((const void*)attn, attn, wprojT, bp, d_out, flag, 2);
}

// Round 3
// 1028.602 us; speedup vs baseline: 1.0178x; 1.0178x over previous
//
#include <hip/hip_runtime.h>
#include <hip/hip_bf16.h>
#include <stdint.h>

typedef __bf16 bf16;
typedef __bf16 bf16x8 __attribute__((ext_vector_type(8)));
typedef float f32x4 __attribute__((ext_vector_type(4)));
typedef unsigned short u16t;
typedef unsigned int u32t;

#define MFMA16(a, b, c) __builtin_amdgcn_mfma_f32_16x16x32_bf16((a), (b), (c), 0, 0, 0)

typedef const void __attribute__((address_space(1))) cg_void;
typedef void __attribute__((address_space(3))) lds_void;
#define GLL16(g, l) __builtin_amdgcn_global_load_lds((cg_void*)(g), (lds_void*)(l), 16, 0, 0)
#define VWAIT(n) asm volatile("s_waitcnt vmcnt(" #n ")" ::: "memory")

// ---------------- ws layout (bytes) ----------------
#define OFF_FLAG   0
#define OFF_BQKV   256
#define OFF_BPROJ  6400
#define OFF_WQKVT  8448
#define OFF_WPROJT 1581312
#define OFF_QKV    2105600
#define OFF_ATTN   404758784
// xb (bf16 copy of x) aliases OFF_ATTN: lifetime-disjoint.
#define OFF_XB     404758784

// ---------------- dtype detector ----------------
__global__ __launch_bounds__(256) void k_detect(const u16t* x, u32t* flag) {
    __shared__ int cnt;
    if (threadIdx.x == 0) cnt = 0;
    __syncthreads();
    u16t h = x[threadIdx.x * 2];
    int e = (h >> 7) & 0xFF;
    int ok = (h == 0) || (e >= 100 && e <= 134);
    atomicAdd(&cnt, ok);
    __syncthreads();
    if (threadIdx.x == 0) flag[0] = (cnt >= 200) ? 1u : 0u;
}

// ---------------- x f32 -> bf16 pre-pass (skipped when input already bf16) ----
__global__ __launch_bounds__(256) void k_cvt(const float* x, bf16* xb, const u32t* flagp) {
    if (flagp[0]) return;
    const size_t TOT = (size_t)131072 * 512;
    size_t i = (size_t)(blockIdx.x * 256 + threadIdx.x) * 8;
    const size_t stride = (size_t)gridDim.x * 256 * 8;
    for (; i < TOT; i += stride) {
        float4 v0 = *(const float4*)(x + i);
        float4 v1 = *(const float4*)(x + i + 4);
        bf16x8 h;
        h[0] = (bf16)v0.x; h[1] = (bf16)v0.y; h[2] = (bf16)v0.z; h[3] = (bf16)v0.w;
        h[4] = (bf16)v1.x; h[5] = (bf16)v1.y; h[6] = (bf16)v1.z; h[7] = (bf16)v1.w;
        *(bf16x8*)(xb + i) = h;
    }
}

// ---------------- weight transpose: W[512][N] -> Wt[N][512] bf16 ----------------
template <int N>
__global__ __launch_bounds__(256) void k_trans(const void* W, bf16* Wt, const u32t* flagp) {
    __shared__ float T[64][65];
    const int isbf = (int)flagp[0];
    const int n0 = blockIdx.x * 64, k0 = blockIdx.y * 64;
    const int t = threadIdx.x;
    const int lc = t & 63, lr = t >> 6;
#pragma unroll
    for (int rr = 0; rr < 16; ++rr) {
        int row = rr * 4 + lr;
        size_t g = (size_t)(k0 + row) * N + n0 + lc;
        float v = isbf ? (float)((const bf16*)W)[g] : ((const float*)W)[g];
        T[row][lc] = v;
    }
    __syncthreads();
#pragma unroll
    for (int rr = 0; rr < 16; ++rr) {
        int row = rr * 4 + lr;
        Wt[(size_t)(n0 + row) * 512 + k0 + lc] = (bf16)T[lc][row];
    }
}

// ---------------- bias prep -> f32 ----------------
__global__ __launch_bounds__(256) void k_bias(const void* b_qkv, const void* b_proj,
                                              const u32t* flagp, char* ws) {
    float* bq = (float*)(ws + OFF_BQKV);
    float* bp = (float*)(ws + OFF_BPROJ);
    const int isbf = (int)flagp[0];
    int gid = blockIdx.x * 256 + threadIdx.x;
    if (gid < 1536)
        bq[gid] = isbf ? (float)((const bf16*)b_qkv)[gid] : ((const float*)b_qkv)[gid];
    else if (gid < 2048) {
        int o = gid - 1536;
        bp[o] = isbf ? (float)((const bf16*)b_proj)[o] : ((const float*)b_proj)[o];
    }
}

// ---------------- GEMM: C[M][NTOT] = A[M][512] * Bt[NTOT][512]^T + bias ----------------
// 256x256 tile (m201 8-phase template), BK=64, 512 threads = 8 waves (2M x 4N),
// per-wave output 128x64 (acc[8][4] f32x4 = 128 VGPR). LDS 128 KiB = 2 K-tile
// buffers x (A 256x64 + B 256x64) bf16. K=512 -> 8 K-tiles, 4 phases each.
//
// Phase (qm,qn): 12 ds_read_b128 (A 4x2kk, B 2x2kk) -> stage 1 half-tile (2 GLL16)
// -> counted vmcnt -> s_barrier -> 16 MFMA (setprio-wrapped) -> s_barrier.
// Stage targets the OTHER K-tile buffer (freed >=2 barriers ago: race-free).
// Half-tile = strip: A strip s = rows {qm==s} (64-row runs), B strip s = rows
// {qn==s} (32-row runs). Stage order per tile {A-s0,B-s0,B-s1,A-s1} matches the
// next tile's consume order; ledger-derived waits vmcnt(4,4,6,4), tail 2->0.
// LDS chunk swizzle: phys chunk = c ^ (row&7); staged via inverse-swizzled global
// source (linear GLL16 dest), read back with the same XOR -> ~2-way (free).
template <int NTOT>
__global__ __launch_bounds__(512, 2) void k_gemm(const void* Ax, const bf16* Axb, const bf16* Bt,
                                                 const float* bias, void* Cp,
                                                 const u32t* flagp, int omode) {
    __shared__ __align__(16) u16t As[2 * 16384];
    __shared__ __align__(16) u16t Bs[2 * 16384];
    constexpr int NBN = NTOT / 256;
    const int isbf = (int)flagp[0];
    const int out_bf16 = (omode == 1) || isbf;
    const bf16* Ab = isbf ? (const bf16*)Ax : Axb;

    const int t = threadIdx.x;
    const int w = t >> 6, lane = t & 63;
    const int ln = lane & 15, qd = lane >> 4;
    const int wm = w >> 2, wn = w & 3;

    // XCD-aware swizzle
    const int flat = blockIdx.x;
    const int xcd = flat & 7, slot = flat >> 3;
    const int n_idx = slot % NBN, grp = slot / NBN;
    const int m0 = (grp * 8 + xcd) * 256;
    const int n0 = n_idx * 256;

    // ---- staging addresses: half-tile strip s, part q2; 2 GLL16 per (matrix,strip)
    const int l8 = lane >> 3, pc = lane & 7;
    const int cs8 = (pc ^ l8) * 8;          // inverse-swizzled source col (elems)
    u32t aoff[2][2], boff[2][2];            // [s][q2] global elem offset at kt=0
    int adst[2][2], bdst[2][2];             // wave-uniform LDS u16 base (buf 0)
#pragma unroll
    for (int s = 0; s < 2; ++s)
#pragma unroll
        for (int q2 = 0; q2 < 2; ++q2) {
            int rA = q2 * 128 + s * 64 + w * 8;                       // A row-run base
            aoff[s][q2] = (u32t)(m0 + rA + l8) * 512 + cs8;
            adst[s][q2] = rA * 64;
            int rB = (q2 * 2 + (w >> 2)) * 64 + s * 32 + (w & 3) * 8; // B row-run base
            boff[s][q2] = (u32t)(n0 + rB + l8) * 512 + cs8;
            bdst[s][q2] = rB * 64;
        }

    // ---- fragment read bases (u16 idx; +qm*4096 / +qn*2048; ^32 for kk=1)
    const int p0 = (qd ^ (ln & 7)) * 8;
    int abase[4], bbase[2];
#pragma unroll
    for (int i = 0; i < 4; ++i) abase[i] = (wm * 128 + i * 16 + ln) * 64 + p0;
#pragma unroll
    for (int j = 0; j < 2; ++j) bbase[j] = (wn * 64 + j * 16 + ln) * 64 + p0;

    f32x4 acc[8][4];
    f32x4 zero = {0.f, 0.f, 0.f, 0.f};
#pragma unroll
    for (int i = 0; i < 8; ++i)
#pragma unroll
        for (int j = 0; j < 4; ++j) acc[i][j] = zero;

    auto stageA = [&](int s, int buf, int kt) {
#pragma unroll
        for (int q2 = 0; q2 < 2; ++q2)
            GLL16(Ab + aoff[s][q2] + kt * 64, &As[buf * 16384 + adst[s][q2]]);
    };
    auto stageB = [&](int s, int buf, int kt) {
#pragma unroll
        for (int q2 = 0; q2 < 2; ++q2)
            GLL16(Bt + boff[s][q2] + kt * 64, &Bs[buf * 16384 + bdst[s][q2]]);
    };

#define PH(BUF, QM, QN, STG, WAITOP)                                             \
    {                                                                            \
        bf16x8 af[4][2], bv[2][2];                                               \
        const u16t* Ap = &As[(BUF) * 16384 + (QM) * 4096];                       \
        const u16t* Bp = &Bs[(BUF) * 16384 + (QN) * 2048];                       \
        _Pragma("unroll") for (int i = 0; i < 4; ++i) {                          \
            af[i][0] = *(const bf16x8*)(const void*)&Ap[abase[i]];               \
            af[i][1] = *(const bf16x8*)(const void*)&Ap[abase[i] ^ 32];          \
        }                                                                        \
        _Pragma("unroll") for (int j = 0; j < 2; ++j) {                          \
            bv[j][0] = *(const bf16x8*)(const void*)&Bp[bbase[j]];               \
            bv[j][1] = *(const bf16x8*)(const void*)&Bp[bbase[j] ^ 32];          \
        }                                                                        \
        STG;                                                                     \
        WAITOP;                                                                  \
        __builtin_amdgcn_s_barrier();                                            \
        __builtin_amdgcn_s_setprio(1);                                           \
        _Pragma("unroll") for (int i = 0; i < 4; ++i)                            \
            _Pragma("unroll") for (int j = 0; j < 2; ++j) {                      \
                acc[(QM) * 4 + i][(QN) * 2 + j] =                                \
                    MFMA16(af[i][0], bv[j][0], acc[(QM) * 4 + i][(QN) * 2 + j]); \
                acc[(QM) * 4 + i][(QN) * 2 + j] =                                \
                    MFMA16(af[i][1], bv[j][1], acc[(QM) * 4 + i][(QN) * 2 + j]); \
            }                                                                    \
        __builtin_amdgcn_s_setprio(0);                                           \
        __builtin_amdgcn_s_barrier();                                            \
    }

    // prologue: tile 0 -> buf0, in consume order; wait for A-s0,B-s0
    stageA(0, 0, 0);
    stageB(0, 0, 0);
    stageB(1, 0, 0);
    stageA(1, 0, 0);
    VWAIT(4);
    __builtin_amdgcn_s_barrier();

    for (int kt = 0; kt < 7; ++kt) {
        const int buf = kt & 1, nb = buf ^ 1, k1 = kt + 1;
        PH(buf, 0, 0, stageA(0, nb, k1), VWAIT(4));
        PH(buf, 0, 1, stageB(0, nb, k1), VWAIT(4));
        PH(buf, 1, 0, stageB(1, nb, k1), VWAIT(6));
        PH(buf, 1, 1, stageA(1, nb, k1), VWAIT(4));
    }
    // tile 7 (buf1): no staging; drain 2 -> 0
    PH(1, 0, 0, (void)0, VWAIT(2));
    PH(1, 0, 1, (void)0, VWAIT(0));
    PH(1, 1, 0, (void)0, (void)0);
    PH(1, 1, 1, (void)0, (void)0);
#undef PH

    float bj[4];
#pragma unroll
    for (int j = 0; j < 4; ++j) bj[j] = bias[n0 + wn * 64 + j * 16 + ln];

    if (out_bf16) {
        bf16* C = (bf16*)Cp;
#pragma unroll
        for (int i = 0; i < 8; ++i)
#pragma unroll
            for (int j = 0; j < 4; ++j)
#pragma unroll
                for (int rr = 0; rr < 4; ++rr) {
                    size_t row = (size_t)m0 + wm * 128 + i * 16 + qd * 4 + rr;
                    int col = n0 + wn * 64 + j * 16 + ln;
                    C[row * NTOT + col] = (bf16)(acc[i][j][rr] + bj[j]);
                }
    } else {
        float* C = (float*)Cp;
#pragma unroll
        for (int i = 0; i < 8; ++i)
#pragma unroll
            for (int j = 0; j < 4; ++j)
#pragma unroll
                for (int rr = 0; rr < 4; ++rr) {
                    size_t row = (size_t)m0 + wm * 128 + i * 16 + qd * 4 + rr;
                    int col = n0 + wn * 64 + j * 16 + ln;
                    C[row * NTOT + col] = acc[i][j][rr] + bj[j];
                }
    }
}

// ---------------- fused gaussian-window attention: one wave per (b,h) ----------------
__global__ __launch_bounds__(256) void k_attn(const bf16* qkv, bf16* attn) {
    __shared__ __align__(16) bf16 P[4][64 * 72];
    __shared__ __align__(16) u16t Vs[4][2048];   // 4 KB per wave: V[64][32] swizzled
    const int t = threadIdx.x;
    const int w = t >> 6, lane = t & 63;
    const int ln = lane & 15, qd = lane >> 4, q8 = qd * 8;
    const int flat = blockIdx.x;
    const int xcd = flat & 7, slot = flat >> 3;
    const int sub = slot & 3, grp = slot >> 2;
    const int b = grp * 8 + xcd;
    const int h = sub * 4 + w;
    const size_t rowbase = (size_t)b * 64 * 1536;
    const int colq = h * 32 + q8;

    bf16x8 aq[4], bk[4];
#pragma unroll
    for (int i = 0; i < 4; ++i)
        aq[i] = *(const bf16x8*)(qkv + rowbase + (size_t)(i * 16 + ln) * 1536 + colq);
#pragma unroll
    for (int j = 0; j < 4; ++j)
        bk[j] = *(const bf16x8*)(qkv + rowbase + (size_t)(j * 16 + ln) * 1536 + 512 + colq);

    // V stage: phys chunk = q*64+lane; r = phys>>2, pc = phys&3, logical c = pc ^ fv(r)
#pragma unroll
    for (int q = 0; q < 4; ++q) {
        int r = q * 16 + (lane >> 2), pc = lane & 3;
        int c = pc ^ (((r >> 3) ^ r) & 3);
        GLL16(qkv + rowbase + (size_t)r * 1536 + 1024 + h * 32 + c * 8, &Vs[w][q * 512]);
    }

    f32x4 zero = {0.f, 0.f, 0.f, 0.f};
    f32x4 s[4][4];
#pragma unroll
    for (int i = 0; i < 4; ++i)
#pragma unroll
        for (int j = 0; j < 4; ++j) s[i][j] = MFMA16(aq[i], bk[j], zero);

    const float INV2S2 = 3.28731097961867f;   // 1/(2*0.39^2)
    {
        int c = lane & 7;
        float S1 = 0.f;
#pragma unroll
        for (int c2 = 0; c2 < 8; ++c2) {
            int d = c - c2;
            S1 += __expf(-(float)(d * d) * INV2S2);
        }
        float invS1 = 1.0f / S1;
        const int ymb = ln >> 3, xm = ln & 7, yq = qd >> 1, xq = (qd & 1) * 4;
        float FY[4][4], FX[4];
#pragma unroll
        for (int i = 0; i < 4; ++i) {
            int yn = 2 * i + yq;
            float g = __shfl(invS1, yn, 64);
#pragma unroll
            for (int j = 0; j < 4; ++j) {
                int dy = yn - (2 * j + ymb);
                FY[i][j] = __expf(-(float)(dy * dy) * INV2S2) * g;
            }
        }
#pragma unroll
        for (int rr = 0; rr < 4; ++rr) {
            int xn = xq + rr;
            int dx = xn - xm;
            FX[rr] = __expf(-(float)(dx * dx) * INV2S2) * __shfl(invS1, xn, 64);
        }

        const float SCALE = 0.17677669529663687f;  // 1/sqrt(32)
#pragma unroll
        for (int i = 0; i < 4; ++i)
#pragma unroll
            for (int rr = 0; rr < 4; ++rr) {
                float lj[4];
                float mx = -1e30f;
#pragma unroll
                for (int j = 0; j < 4; ++j) {
                    lj[j] = s[i][j][rr] * SCALE * FY[i][j] * FX[rr];
                    mx = fmaxf(mx, lj[j]);
                }
                mx = fmaxf(mx, __shfl_xor(mx, 1));
                mx = fmaxf(mx, __shfl_xor(mx, 2));
                mx = fmaxf(mx, __shfl_xor(mx, 4));
                mx = fmaxf(mx, __shfl_xor(mx, 8));
                float sum = 0.f;
#pragma unroll
                for (int j = 0; j < 4; ++j) {
                    lj[j] = __expf(lj[j] - mx);
                    sum += lj[j];
                }
                sum += __shfl_xor(sum, 1);
                sum += __shfl_xor(sum, 2);
                sum += __shfl_xor(sum, 4);
                sum += __shfl_xor(sum, 8);
                float inv = 1.0f / sum;
                int n = i * 16 + qd * 4 + rr;
#pragma unroll
                for (int j = 0; j < 4; ++j)
                    P[w][n * 72 + j * 16 + ln] = (bf16)(lj[j] * inv);
            }
    }

    VWAIT(0);   // wave-local V tile staged; no barrier needed

    f32x4 o[4][2];
#pragma unroll
    for (int i = 0; i < 4; ++i) {
        o[i][0] = zero;
        o[i][1] = zero;
    }
#pragma unroll
    for (int kc = 0; kc < 64; kc += 32) {
        bf16x8 bv[2];
#pragma unroll
        for (int j2 = 0; j2 < 2; ++j2) {
            int cc = j2 * 2 + (ln >> 3);
#pragma unroll
            for (int jj = 0; jj < 8; ++jj) {
                int rv = kc + q8 + jj;
                bv[j2][jj] = *(const bf16*)&Vs[w][rv * 32 + (cc ^ (((rv >> 3) ^ rv) & 3)) * 8 + (ln & 7)];
            }
        }
#pragma unroll
        for (int i = 0; i < 4; ++i) {
            bf16x8 ap = *(const bf16x8*)(void*)&P[w][(i * 16 + ln) * 72 + kc + q8];
#pragma unroll
            for (int j2 = 0; j2 < 2; ++j2) o[i][j2] = MFMA16(ap, bv[j2], o[i][j2]);
        }
    }
#pragma unroll
    for (int i = 0; i < 4; ++i)
#pragma unroll
        for (int j2 = 0; j2 < 2; ++j2)
#pragma unroll
            for (int rr = 0; rr < 4; ++rr)
                attn[((size_t)b * 64 + i * 16 + qd * 4 + rr) * 512 + h * 32 + j2 * 16 + ln] =
                    (bf16)(o[i][j2][rr]);
}

extern "C" void kernel_launch(void* const* d_in, const int* in_sizes, int n_in,
                              void* d_out, int out_size, void* d_ws, size_t ws_size,
                              hipStream_t stream) {
    const void* x = d_in[0];
    const void* w_qkv = d_in[1];
    const void* b_qkv = d_in[2];
    const void* w_proj = d_in[3];
    const void* b_proj = d_in[4];
    char* ws = (char*)d_ws;
    u32t* flag = (u32t*)(ws + OFF_FLAG);
    bf16* wqkvT = (bf16*)(ws + OFF_WQKVT);
    bf16* wprojT = (bf16*)(ws + OFF_WPROJT);
    float* bq = (float*)(ws + OFF_BQKV);
    float* bp = (float*)(ws + OFF_BPROJ);
    bf16* qkv = (bf16*)(ws + OFF_QKV);
    bf16* attn = (bf16*)(ws + OFF_ATTN);
    bf16* xb = (bf16*)(ws + OFF_XB);   // aliases attn region (disjoint lifetime)

    k_detect<<<1, 256, 0, stream>>>((const u16t*)x, flag);
    k_cvt<<<2048, 256, 0, stream>>>((const float*)x, xb, flag);
    k_trans<1536><<<dim3(24, 8), 256, 0, stream>>>(w_qkv, wqkvT, flag);
    k_trans<512><<<dim3(8, 8), 256, 0, stream>>>(w_proj, wprojT, flag);
    k_bias<<<8, 256, 0, stream>>>(b_qkv, b_proj, flag, ws);
    // QKV GEMM: [131072,512] @ [512,1536] -> qkv bf16 (512*6 = 3072 blocks, 512 thr)
    k_gemm<1536><<<3072, 512, 0, stream>>>(x, xb, wqkvT, bq, qkv, flag, 1);
    // attention
    k_attn<<<8192, 256, 0, stream>>>(qkv, attn);
    // proj GEMM: [131072,512] @ [512,512] -> d_out (512*2 = 1024 blocks)
    k_gemm<512><<<1024, 512, 0, stream>>>((const void*)attn, attn, wprojT, bp, d_out, flag, 2);
}

// Round 5
// 953.244 us; speedup vs baseline: 1.0983x; 1.0791x over previous
//
#include <hip/hip_runtime.h>
#include <hip/hip_bf16.h>
#include <stdint.h>

typedef __bf16 bf16;
typedef __bf16 bf16x8 __attribute__((ext_vector_type(8)));
typedef float f32x4 __attribute__((ext_vector_type(4)));
typedef unsigned short u16t;
typedef unsigned int u32t;

#define MFMA16(a, b, c) __builtin_amdgcn_mfma_f32_16x16x32_bf16((a), (b), (c), 0, 0, 0)

typedef const void __attribute__((address_space(1))) cg_void;
typedef void __attribute__((address_space(3))) lds_void;
#define GLL16(g, l) __builtin_amdgcn_global_load_lds((cg_void*)(g), (lds_void*)(l), 16, 0, 0)
#define VWAIT(n) asm volatile("s_waitcnt vmcnt(" #n ")" ::: "memory")

// ---------------- ws layout (bytes) ----------------
#define OFF_FLAG   0
#define OFF_BQKV   256
#define OFF_BPROJ  6400
#define OFF_WQKVT  8448
#define OFF_WPROJT 1581312
#define OFF_QKV    2105600      // now holds attn-out (134 MB; qkv never materialized)
#define OFF_ATTN   404758784
#define OFF_XB     404758784    // xb (bf16 x) lives here; attn-out moved to OFF_QKV

// head-triple permutation: reordered-W^T row n <- original qkv col src(n)
// h = n/96, r = n%96, part = r/32 (0=Q,1=K,2=V), d = r%32; src = part*512 + h*32 + d

// ---------------- dtype detector ----------------
__global__ __launch_bounds__(256) void k_detect(const u16t* x, u32t* flag) {
    __shared__ int cnt;
    if (threadIdx.x == 0) cnt = 0;
    __syncthreads();
    u16t h = x[threadIdx.x * 2];
    int e = (h >> 7) & 0xFF;
    int ok = (h == 0) || (e >= 100 && e <= 134);
    atomicAdd(&cnt, ok);
    __syncthreads();
    if (threadIdx.x == 0) flag[0] = (cnt >= 200) ? 1u : 0u;
}

// ---------------- x f32 -> bf16 pre-pass (skipped when input already bf16) ----
__global__ __launch_bounds__(256) void k_cvt(const float* x, bf16* xb, const u32t* flagp) {
    if (flagp[0]) return;
    const size_t TOT = (size_t)131072 * 512;
    size_t i = (size_t)(blockIdx.x * 256 + threadIdx.x) * 8;
    const size_t stride = (size_t)gridDim.x * 256 * 8;
    for (; i < TOT; i += stride) {
        float4 v0 = *(const float4*)(x + i);
        float4 v1 = *(const float4*)(x + i + 4);
        bf16x8 h;
        h[0] = (bf16)v0.x; h[1] = (bf16)v0.y; h[2] = (bf16)v0.z; h[3] = (bf16)v0.w;
        h[4] = (bf16)v1.x; h[5] = (bf16)v1.y; h[6] = (bf16)v1.z; h[7] = (bf16)v1.w;
        *(bf16x8*)(xb + i) = h;
    }
}

// ---------------- weight transpose: W[512][N] -> Wt[N][512] bf16 ----------------
// PERM: apply head-triple column permutation (for w_qkv).
template <int N, bool PERM>
__global__ __launch_bounds__(256) void k_trans(const void* W, bf16* Wt, const u32t* flagp) {
    __shared__ float T[64][65];
    const int isbf = (int)flagp[0];
    const int n0 = blockIdx.x * 64, k0 = blockIdx.y * 64;
    const int t = threadIdx.x;
    const int lc = t & 63, lr = t >> 6;
#pragma unroll
    for (int rr = 0; rr < 16; ++rr) {
        int row = rr * 4 + lr;
        int col = n0 + lc;
        int srcc = col;
        if (PERM) {
            int h = col / 96, r = col % 96;
            srcc = (r >> 5) * 512 + h * 32 + (r & 31);
        }
        size_t g = (size_t)(k0 + row) * N + srcc;
        float v = isbf ? (float)((const bf16*)W)[g] : ((const float*)W)[g];
        T[row][lc] = v;
    }
    __syncthreads();
#pragma unroll
    for (int rr = 0; rr < 16; ++rr) {
        int row = rr * 4 + lr;
        Wt[(size_t)(n0 + row) * 512 + k0 + lc] = (bf16)T[lc][row];
    }
}

// ---------------- bias prep -> f32 (bq permuted to head-triple order) ----------
__global__ __launch_bounds__(256) void k_bias(const void* b_qkv, const void* b_proj,
                                              const u32t* flagp, char* ws) {
    float* bq = (float*)(ws + OFF_BQKV);
    float* bp = (float*)(ws + OFF_BPROJ);
    const int isbf = (int)flagp[0];
    int gid = blockIdx.x * 256 + threadIdx.x;
    if (gid < 1536) {
        int h = gid / 96, r = gid % 96;
        int src = (r >> 5) * 512 + h * 32 + (r & 31);
        bq[gid] = isbf ? (float)((const bf16*)b_qkv)[src] : ((const float*)b_qkv)[src];
    } else if (gid < 2048) {
        int o = gid - 1536;
        bp[o] = isbf ? (float)((const bf16*)b_proj)[o] : ((const float*)b_proj)[o];
    }
}

// ---------------- proj GEMM (round-3 256^2 8-phase template, unchanged) -------
template <int NTOT>
__global__ __launch_bounds__(512, 2) void k_gemm(const void* Ax, const bf16* Axb, const bf16* Bt,
                                                 const float* bias, void* Cp,
                                                 const u32t* flagp, int omode) {
    __shared__ __align__(16) u16t As[2 * 16384];
    __shared__ __align__(16) u16t Bs[2 * 16384];
    constexpr int NBN = NTOT / 256;
    const int isbf = (int)flagp[0];
    const int out_bf16 = (omode == 1) || isbf;
    const bf16* Ab = isbf ? (const bf16*)Ax : Axb;

    const int t = threadIdx.x;
    const int w = t >> 6, lane = t & 63;
    const int ln = lane & 15, qd = lane >> 4;
    const int wm = w >> 2, wn = w & 3;

    const int flat = blockIdx.x;
    const int xcd = flat & 7, slot = flat >> 3;
    const int n_idx = slot % NBN, grp = slot / NBN;
    const int m0 = (grp * 8 + xcd) * 256;
    const int n0 = n_idx * 256;

    const int l8 = lane >> 3, pc = lane & 7;
    const int cs8 = (pc ^ l8) * 8;
    u32t aoff[2][2], boff[2][2];
    int adst[2][2], bdst[2][2];
#pragma unroll
    for (int s = 0; s < 2; ++s)
#pragma unroll
        for (int q2 = 0; q2 < 2; ++q2) {
            int rA = q2 * 128 + s * 64 + w * 8;
            aoff[s][q2] = (u32t)(m0 + rA + l8) * 512 + cs8;
            adst[s][q2] = rA * 64;
            int rB = (q2 * 2 + (w >> 2)) * 64 + s * 32 + (w & 3) * 8;
            boff[s][q2] = (u32t)(n0 + rB + l8) * 512 + cs8;
            bdst[s][q2] = rB * 64;
        }

    const int p0 = (qd ^ (ln & 7)) * 8;
    int abase[4], bbase[2];
#pragma unroll
    for (int i = 0; i < 4; ++i) abase[i] = (wm * 128 + i * 16 + ln) * 64 + p0;
#pragma unroll
    for (int j = 0; j < 2; ++j) bbase[j] = (wn * 64 + j * 16 + ln) * 64 + p0;

    f32x4 acc[8][4];
    f32x4 zero = {0.f, 0.f, 0.f, 0.f};
#pragma unroll
    for (int i = 0; i < 8; ++i)
#pragma unroll
        for (int j = 0; j < 4; ++j) acc[i][j] = zero;

    auto stageA = [&](int s, int buf, int kt) {
#pragma unroll
        for (int q2 = 0; q2 < 2; ++q2)
            GLL16(Ab + aoff[s][q2] + kt * 64, &As[buf * 16384 + adst[s][q2]]);
    };
    auto stageB = [&](int s, int buf, int kt) {
#pragma unroll
        for (int q2 = 0; q2 < 2; ++q2)
            GLL16(Bt + boff[s][q2] + kt * 64, &Bs[buf * 16384 + bdst[s][q2]]);
    };

#define PH(BUF, QM, QN, STG, WAITOP)                                             \
    {                                                                            \
        bf16x8 af[4][2], bv[2][2];                                               \
        const u16t* Ap = &As[(BUF) * 16384 + (QM) * 4096];                       \
        const u16t* Bp = &Bs[(BUF) * 16384 + (QN) * 2048];                       \
        _Pragma("unroll") for (int i = 0; i < 4; ++i) {                          \
            af[i][0] = *(const bf16x8*)(const void*)&Ap[abase[i]];               \
            af[i][1] = *(const bf16x8*)(const void*)&Ap[abase[i] ^ 32];          \
        }                                                                        \
        _Pragma("unroll") for (int j = 0; j < 2; ++j) {                          \
            bv[j][0] = *(const bf16x8*)(const void*)&Bp[bbase[j]];               \
            bv[j][1] = *(const bf16x8*)(const void*)&Bp[bbase[j] ^ 32];          \
        }                                                                        \
        STG;                                                                     \
        WAITOP;                                                                  \
        __builtin_amdgcn_s_barrier();                                            \
        __builtin_amdgcn_s_setprio(1);                                           \
        _Pragma("unroll") for (int i = 0; i < 4; ++i)                            \
            _Pragma("unroll") for (int j = 0; j < 2; ++j) {                      \
                acc[(QM) * 4 + i][(QN) * 2 + j] =                                \
                    MFMA16(af[i][0], bv[j][0], acc[(QM) * 4 + i][(QN) * 2 + j]); \
                acc[(QM) * 4 + i][(QN) * 2 + j] =                                \
                    MFMA16(af[i][1], bv[j][1], acc[(QM) * 4 + i][(QN) * 2 + j]); \
            }                                                                    \
        __builtin_amdgcn_s_setprio(0);                                           \
        __builtin_amdgcn_s_barrier();                                            \
    }

    stageA(0, 0, 0);
    stageB(0, 0, 0);
    stageB(1, 0, 0);
    stageA(1, 0, 0);
    VWAIT(4);
    __builtin_amdgcn_s_barrier();

    for (int kt = 0; kt < 7; ++kt) {
        const int buf = kt & 1, nb = buf ^ 1, k1 = kt + 1;
        PH(buf, 0, 0, stageA(0, nb, k1), VWAIT(4));
        PH(buf, 0, 1, stageB(0, nb, k1), VWAIT(4));
        PH(buf, 1, 0, stageB(1, nb, k1), VWAIT(6));
        PH(buf, 1, 1, stageA(1, nb, k1), VWAIT(4));
    }
    PH(1, 0, 0, (void)0, VWAIT(2));
    PH(1, 0, 1, (void)0, VWAIT(0));
    PH(1, 1, 0, (void)0, (void)0);
    PH(1, 1, 1, (void)0, (void)0);
#undef PH

    float bj[4];
#pragma unroll
    for (int j = 0; j < 4; ++j) bj[j] = bias[n0 + wn * 64 + j * 16 + ln];

    if (out_bf16) {
        bf16* C = (bf16*)Cp;
#pragma unroll
        for (int i = 0; i < 8; ++i)
#pragma unroll
            for (int j = 0; j < 4; ++j)
#pragma unroll
                for (int rr = 0; rr < 4; ++rr) {
                    size_t row = (size_t)m0 + wm * 128 + i * 16 + qd * 4 + rr;
                    int col = n0 + wn * 64 + j * 16 + ln;
                    C[row * NTOT + col] = (bf16)(acc[i][j][rr] + bj[j]);
                }
    } else {
        float* C = (float*)Cp;
#pragma unroll
        for (int i = 0; i < 8; ++i)
#pragma unroll
            for (int j = 0; j < 4; ++j)
#pragma unroll
                for (int rr = 0; rr < 4; ++rr) {
                    size_t row = (size_t)m0 + wm * 128 + i * 16 + qd * 4 + rr;
                    int col = n0 + wn * 64 + j * 16 + ln;
                    C[row * NTOT + col] = acc[i][j][rr] + bj[j];
                }
    }
}

// ---------------- FUSED QKV GEMM + gaussian-window attention ----------------
// Block: BM=256 tokens (4 windows) x BN=192 cols (2 heads' {Q|K|V} triples,
// via permuted Wt). 512 thr = 8 waves; GEMM partition 2M x 4N (wave 128x48,
// acc[8][3]). K=512 -> 8 K-tiles BK=64, 4 phases each (qm x kk), counted vmcnt.
// Epilogue: stash Q,K,V (+bias, bf16) into 8 per-(window,head) LDS patches;
// barrier; wave w runs attention for pair (window=w>>1, head=w&1) -- identical
// math to the former k_attn -- and writes only attn-out (no qkv materialized).
//
// LDS pool 114688 B: staging A[2][16384]u16 @0, B[2][12288]u16 @32768.
// Attn patches (after final barrier, reuse): patch w @ w*6656 u16:
//   Q [0,2048) row-major 64x32, chunk-swz c^((r>>1)&3)
//   K [2048,4096) same; P overlays [0,4608) stride-72 after Q/K frags read
//   V [4608,6656) chunk-swz c^(((r>>3)^r)&3)
// vmcnt ledger (7 loads/tile, issue order A0,A2|B0,B1|B2,A1|A3):
//   invariant at tile start: {A0,A2,B*} done, {A1,A3} in flight.
//   P1: VWAIT(4) (completes A1,A3 for P2's reads); P3: VWAIT(2) (completes
//   next tile's A0,A2,B*). Tail: P1 VWAIT(0). Never drains mid-loop.
__global__ __launch_bounds__(512, 2) void k_fused(const void* Ax, const bf16* Axb,
                                                  const bf16* Bt, const float* bias,
                                                  bf16* attnout, const u32t* flagp) {
    __shared__ __align__(16) u16t pool[57344];
    const int isbf = (int)flagp[0];
    const bf16* Ab = isbf ? (const bf16*)Ax : Axb;

    const int t = threadIdx.x;
    const int w = t >> 6, lane = t & 63;
    const int ln = lane & 15, qd = lane >> 4, q8 = qd * 8;
    const int wm = w >> 2, wn = w & 3;

    const int flat = blockIdx.x;
    const int xcd = flat & 7, slot = flat >> 3;
    const int n_idx = slot & 7, grp = slot >> 3;
    const int m0 = (grp * 8 + xcd) * 256;
    const int n0 = n_idx * 192;

    // staging addresses
    const int l8 = lane >> 3, pc = lane & 7;
    const int cs8 = (pc ^ l8) * 8;
    u32t aoff[4], boff[3];
    int adst[4], bdst[3];
#pragma unroll
    for (int qa = 0; qa < 4; ++qa) {
        int row = qa * 64 + w * 8 + l8;
        aoff[qa] = (u32t)(m0 + row) * 512 + cs8;
        adst[qa] = (qa * 512 + w * 64) * 8;
    }
#pragma unroll
    for (int qb = 0; qb < 3; ++qb) {
        int row = qb * 64 + w * 8 + l8;
        boff[qb] = (u32t)(n0 + row) * 512 + cs8;
        bdst[qb] = (qb * 512 + w * 64) * 8;
    }

    // fragment read bases (u16 idx within buf; ^32 for kk=1)
    const int swz = (qd ^ (ln & 7)) * 8;
    int afo[2][4], bfo[3];
#pragma unroll
    for (int qm = 0; qm < 2; ++qm)
#pragma unroll
        for (int i = 0; i < 4; ++i)
            afo[qm][i] = (wm * 128 + qm * 64 + i * 16 + ln) * 64 + swz;
#pragma unroll
    for (int j = 0; j < 3; ++j) bfo[j] = (wn * 48 + j * 16 + ln) * 64 + swz;

    f32x4 acc[8][3];
    f32x4 zero = {0.f, 0.f, 0.f, 0.f};
#pragma unroll
    for (int i = 0; i < 8; ++i)
#pragma unroll
        for (int j = 0; j < 3; ++j) acc[i][j] = zero;

    auto stA = [&](int qa, int buf, int kt) {
        GLL16(Ab + aoff[qa] + kt * 64, &pool[buf * 16384 + adst[qa]]);
    };
    auto stB = [&](int qb, int buf, int kt) {
        GLL16(Bt + boff[qb] + kt * 64, &pool[32768 + buf * 12288 + bdst[qb]]);
    };

#define PHF(BUF, QM, KK, STG, WAITOP)                                           \
    {                                                                           \
        bf16x8 af[4], bv[3];                                                    \
        _Pragma("unroll") for (int i = 0; i < 4; ++i)                           \
            af[i] = *(const bf16x8*)(const void*)                               \
                &pool[(BUF) * 16384 + (afo[QM][i] ^ ((KK) * 32))];              \
        _Pragma("unroll") for (int j = 0; j < 3; ++j)                           \
            bv[j] = *(const bf16x8*)(const void*)                               \
                &pool[32768 + (BUF) * 12288 + (bfo[j] ^ ((KK) * 32))];          \
        STG;                                                                    \
        WAITOP;                                                                 \
        __builtin_amdgcn_s_barrier();                                           \
        __builtin_amdgcn_s_setprio(1);                                          \
        _Pragma("unroll") for (int i = 0; i < 4; ++i)                           \
            _Pragma("unroll") for (int j = 0; j < 3; ++j)                       \
                acc[(QM) * 4 + i][j] = MFMA16(af[i], bv[j], acc[(QM) * 4 + i][j]); \
        __builtin_amdgcn_s_setprio(0);                                          \
        __builtin_amdgcn_s_barrier();                                           \
    }

    // prologue: tile 0 -> buf 0, issue order matches ledger
    stA(0, 0, 0); stA(2, 0, 0);
    stB(0, 0, 0); stB(1, 0, 0); stB(2, 0, 0);
    stA(1, 0, 0); stA(3, 0, 0);
    VWAIT(2);
    __builtin_amdgcn_s_barrier();

    for (int kt = 0; kt < 7; ++kt) {
        const int buf = kt & 1, nb = buf ^ 1, k1 = kt + 1;
        PHF(buf, 0, 0, (stA(0, nb, k1), stA(2, nb, k1)), (void)0);
        PHF(buf, 0, 1, (stB(0, nb, k1), stB(1, nb, k1)), VWAIT(4));
        PHF(buf, 1, 0, (stB(2, nb, k1), stA(1, nb, k1)), (void)0);
        PHF(buf, 1, 1, (stA(3, nb, k1)), VWAIT(2));
    }
    PHF(1, 0, 0, (void)0, (void)0);
    PHF(1, 0, 1, (void)0, VWAIT(0));
    PHF(1, 1, 0, (void)0, (void)0);
    PHF(1, 1, 1, (void)0, (void)0);
#undef PHF

    // ---- stash Q,K,V (+bias) into per-(window,head) patches ----
    float bj[3];
#pragma unroll
    for (int j = 0; j < 3; ++j) bj[j] = bias[n0 + wn * 48 + j * 16 + ln];

#pragma unroll
    for (int i = 0; i < 8; ++i) {
        int win = wm * 2 + (i >> 2);
#pragma unroll
        for (int j = 0; j < 3; ++j) {
            int base = wn * 48 + j * 16;
            int hl = base >= 96;
            int bb = base - hl * 96;
            int part = bb >> 5;        // 0=Q 1=K 2=V
            int d = (bb & 31) + ln;
            int patch = (win * 2 + hl) * 6656;
#pragma unroll
            for (int rr = 0; rr < 4; ++rr) {
                int tok = (i & 3) * 16 + qd * 4 + rr;
                bf16 val = (bf16)(acc[i][j][rr] + bj[j]);
                int idx;
                if (part == 2)
                    idx = patch + 4608 + tok * 32 +
                          (((d >> 3) ^ (((tok >> 3) ^ tok) & 3)) << 3) + (d & 7);
                else
                    idx = patch + part * 2048 + tok * 32 +
                          (((d >> 3) ^ ((tok >> 1) & 3)) << 3) + (d & 7);
                *(bf16*)&pool[idx] = val;
            }
        }
    }
    __syncthreads();

    // ---- attention: wave w handles (window = w>>1, head-local = w&1) ----
    {
        const int patch = w * 6656;
        const int win = w >> 1, hl = w & 1;
        const int hcol = (n_idx * 2 + hl) * 32;
        const int qswz = (qd ^ ((ln >> 1) & 3)) * 8;

        bf16x8 aq[4], bk[4];
#pragma unroll
        for (int i = 0; i < 4; ++i)
            aq[i] = *(const bf16x8*)(const void*)&pool[patch + (i * 16 + ln) * 32 + qswz];
#pragma unroll
        for (int j = 0; j < 4; ++j)
            bk[j] = *(const bf16x8*)(const void*)&pool[patch + 2048 + (j * 16 + ln) * 32 + qswz];

        f32x4 zro = {0.f, 0.f, 0.f, 0.f};
        f32x4 s[4][4];
#pragma unroll
        for (int i = 0; i < 4; ++i)
#pragma unroll
            for (int j = 0; j < 4; ++j) s[i][j] = MFMA16(aq[i], bk[j], zro);

        const float INV2S2 = 3.28731097961867f;  // 1/(2*0.39^2)
        {
            int c = lane & 7;
            float S1 = 0.f;
#pragma unroll
            for (int c2 = 0; c2 < 8; ++c2) {
                int dd = c - c2;
                S1 += __expf(-(float)(dd * dd) * INV2S2);
            }
            float invS1 = 1.0f / S1;
            const int ymb = ln >> 3, xm = ln & 7, yq = qd >> 1, xq = (qd & 1) * 4;
            float FY[4][4], FX[4];
#pragma unroll
            for (int i = 0; i < 4; ++i) {
                int yn = 2 * i + yq;
                float g = __shfl(invS1, yn, 64);
#pragma unroll
                for (int j = 0; j < 4; ++j) {
                    int dy = yn - (2 * j + ymb);
                    FY[i][j] = __expf(-(float)(dy * dy) * INV2S2) * g;
                }
            }
#pragma unroll
            for (int rr = 0; rr < 4; ++rr) {
                int xn = xq + rr;
                int dx = xn - xm;
                FX[rr] = __expf(-(float)(dx * dx) * INV2S2) * __shfl(invS1, xn, 64);
            }

            const float SCALE = 0.17677669529663687f;  // 1/sqrt(32)
#pragma unroll
            for (int i = 0; i < 4; ++i)
#pragma unroll
                for (int rr = 0; rr < 4; ++rr) {
                    float lj[4];
                    float mx = -1e30f;
#pragma unroll
                    for (int j = 0; j < 4; ++j) {
                        lj[j] = s[i][j][rr] * SCALE * FY[i][j] * FX[rr];
                        mx = fmaxf(mx, lj[j]);
                    }
                    mx = fmaxf(mx, __shfl_xor(mx, 1));
                    mx = fmaxf(mx, __shfl_xor(mx, 2));
                    mx = fmaxf(mx, __shfl_xor(mx, 4));
                    mx = fmaxf(mx, __shfl_xor(mx, 8));
                    float sum = 0.f;
#pragma unroll
                    for (int j = 0; j < 4; ++j) {
                        lj[j] = __expf(lj[j] - mx);
                        sum += lj[j];
                    }
                    sum += __shfl_xor(sum, 1);
                    sum += __shfl_xor(sum, 2);
                    sum += __shfl_xor(sum, 4);
                    sum += __shfl_xor(sum, 8);
                    float inv = 1.0f / sum;
                    int n = i * 16 + qd * 4 + rr;
#pragma unroll
                    for (int j = 0; j < 4; ++j) {
                        bf16 pv = (bf16)(lj[j] * inv);
                        *(bf16*)&pool[patch + n * 72 + j * 16 + ln] = pv;
                    }
                }
        }

        f32x4 o[4][2];
#pragma unroll
        for (int i = 0; i < 4; ++i) {
            o[i][0] = zro;
            o[i][1] = zro;
        }
#pragma unroll
        for (int kc = 0; kc < 64; kc += 32) {
            bf16x8 bv2[2];
#pragma unroll
            for (int j2 = 0; j2 < 2; ++j2) {
                int cc = j2 * 2 + (ln >> 3);
#pragma unroll
                for (int jj = 0; jj < 8; ++jj) {
                    int rv = kc + q8 + jj;
                    bv2[j2][jj] = *(const bf16*)&pool[patch + 4608 + rv * 32 +
                                                     ((cc ^ (((rv >> 3) ^ rv) & 3)) << 3) + (ln & 7)];
                }
            }
#pragma unroll
            for (int i = 0; i < 4; ++i) {
                bf16x8 ap = *(const bf16x8*)(const void*)&pool[patch + (i * 16 + ln) * 72 + kc + q8];
#pragma unroll
                for (int j2 = 0; j2 < 2; ++j2) o[i][j2] = MFMA16(ap, bv2[j2], o[i][j2]);
            }
        }
#pragma unroll
        for (int i = 0; i < 4; ++i)
#pragma unroll
            for (int j2 = 0; j2 < 2; ++j2)
#pragma unroll
                for (int rr = 0; rr < 4; ++rr)
                    attnout[((size_t)m0 + win * 64 + i * 16 + qd * 4 + rr) * 512 +
                            hcol + j2 * 16 + ln] = (bf16)(o[i][j2][rr]);
    }
}

extern "C" void kernel_launch(void* const* d_in, const int* in_sizes, int n_in,
                              void* d_out, int out_size, void* d_ws, size_t ws_size,
                              hipStream_t stream) {
    const void* x = d_in[0];
    const void* w_qkv = d_in[1];
    const void* b_qkv = d_in[2];
    const void* w_proj = d_in[3];
    const void* b_proj = d_in[4];
    char* ws = (char*)d_ws;
    u32t* flag = (u32t*)(ws + OFF_FLAG);
    bf16* wqkvT = (bf16*)(ws + OFF_WQKVT);
    bf16* wprojT = (bf16*)(ws + OFF_WPROJT);
    float* bq = (float*)(ws + OFF_BQKV);
    float* bp = (float*)(ws + OFF_BPROJ);
    bf16* attnout = (bf16*)(ws + OFF_QKV);  // qkv never materialized; reuse region
    bf16* xb = (bf16*)(ws + OFF_XB);

    k_detect<<<1, 256, 0, stream>>>((const u16t*)x, flag);
    k_cvt<<<2048, 256, 0, stream>>>((const float*)x, xb, flag);
    k_trans<1536, true><<<dim3(24, 8), 256, 0, stream>>>(w_qkv, wqkvT, flag);
    k_trans<512, false><<<dim3(8, 8), 256, 0, stream>>>(w_proj, wprojT, flag);
    k_bias<<<8, 256, 0, stream>>>(b_qkv, b_proj, flag, ws);
    // fused QKV GEMM + attention: 512 m-groups x 8 head-pair blocks
    k_fused<<<4096, 512, 0, stream>>>(x, xb, wqkvT, bq, attnout, flag);
    // proj GEMM: [131072,512] @ [512,512] -> d_out
    k_gemm<512><<<1024, 512, 0, stream>>>((const void*)attnout, attnout, wprojT, bp, d_out, flag, 2);
}